// Round 9
// baseline (7080.125 us; speedup 1.0000x reference)
//
#include <hip/hip_runtime.h>

#define C 128
#define EPS 1e-5f

typedef __bf16 bf16x8 __attribute__((ext_vector_type(8)));
typedef float f32x4 __attribute__((ext_vector_type(4)));

__device__ __forceinline__ unsigned short f2bf(float f) {
    unsigned int u = __float_as_uint(f);
    unsigned int r = (u + 0x7FFFu + ((u >> 16) & 1u)) >> 16;   // RNE
    return (unsigned short)r;
}

// ---------------- weight convert: WT[m][col][k] = bf16(W_m[k][col]) ----------------
struct WPtrs { const float* p[34]; };

__global__ __launch_bounds__(128) void convert_weights(WPtrs wp, unsigned short* __restrict__ WT)
{
    int m = blockIdx.y, k = blockIdx.x, c = threadIdx.x;      // grid (128, 34)
    float val = wp.p[m][k * C + c];
    WT[((size_t)m * C + c) * C + k] = f2bf(val);
}

// ================= CSR preprocessing =================
// deg/cursor: 14*N ints. off: 14*N+1 (+pad). payload: ET ints.

__global__ __launch_bounds__(256) void hist_k(const int* __restrict__ pre_u,
    const int* __restrict__ suc_u, const int* __restrict__ left_u, const int* __restrict__ right_u,
    int* __restrict__ deg, int E, int E2, int N)
{
    int cs = blockIdx.y;
    const int* u; int len;
    if (cs < 6)       { u = pre_u + (size_t)cs * E;       len = E; }
    else if (cs < 12) { u = suc_u + (size_t)(cs - 6) * E; len = E; }
    else if (cs == 12){ u = left_u;  len = E2; }
    else              { u = right_u; len = E2; }
    int e = blockIdx.x * 256 + threadIdx.x;
    if (e < len) atomicAdd(&deg[(size_t)cs * N + u[e]], 1);
}

__global__ __launch_bounds__(256) void scan1(const int* __restrict__ deg, int* __restrict__ off,
                                             int* __restrict__ bsum, int M)
{
    __shared__ int ts[256];
    int b = blockIdx.x, t = threadIdx.x;
    int base = b * 4096 + t * 16;
    int v[16]; int s = 0;
    #pragma unroll
    for (int j = 0; j < 16; ++j) { int idx = base + j; int x = (idx < M) ? deg[idx] : 0; v[j] = s; s += x; }
    ts[t] = s; __syncthreads();
    for (int o = 1; o < 256; o <<= 1) {
        int x = (t >= o) ? ts[t - o] : 0;
        __syncthreads(); ts[t] += x; __syncthreads();
    }
    int texcl = (t == 0) ? 0 : ts[t - 1];
    if (t == 255) bsum[b] = ts[255];
    #pragma unroll
    for (int j = 0; j < 16; ++j) { int idx = base + j; if (idx < M) off[idx] = texcl + v[j]; }
}

__global__ void scan2(int* __restrict__ bsum, int nb)
{
    __shared__ int s[1024];
    int t = threadIdx.x;
    for (int i = t; i < 1024; i += 256) s[i] = (i < nb) ? bsum[i] : 0;
    __syncthreads();
    if (t == 0) { int run = 0; for (int i = 0; i < nb; ++i) { int x = s[i]; s[i] = run; run += x; } }
    __syncthreads();
    for (int i = t; i < nb; i += 256) bsum[i] = s[i];
}

__global__ __launch_bounds__(256) void scan3(int* __restrict__ off, int* __restrict__ cursor,
                                             const int* __restrict__ bsum, int M)
{
    int i = blockIdx.x * 256 + threadIdx.x;
    if (i >= M) return;
    int val = off[i] + bsum[i >> 12];      // 4096 elems per scan1 block
    int dg = cursor[i];                    // cursor still holds deg
    off[i] = val; cursor[i] = val;
    if (i == M - 1) off[M] = val + dg;     // sentinel = ET
}

__global__ __launch_bounds__(256) void scatter_k(const int* __restrict__ pre_u, const int* __restrict__ pre_v,
    const int* __restrict__ suc_u, const int* __restrict__ suc_v,
    const int* __restrict__ left_u, const int* __restrict__ left_v,
    const int* __restrict__ right_u, const int* __restrict__ right_v,
    int* __restrict__ cursor, int* __restrict__ payload, int E, int E2, int N)
{
    int cs = blockIdx.y;
    const int *u, *v; int len;
    if (cs < 6)       { u = pre_u + (size_t)cs * E;       v = pre_v + (size_t)cs * E;       len = E; }
    else if (cs < 12) { u = suc_u + (size_t)(cs - 6) * E; v = suc_v + (size_t)(cs - 6) * E; len = E; }
    else if (cs == 12){ u = left_u;  v = left_v;  len = E2; }
    else              { u = right_u; v = right_v; len = E2; }
    int e = blockIdx.x * 256 + threadIdx.x;
    if (e < len) {
        int pos = atomicAdd(&cursor[(size_t)cs * N + u[e]], 1);
        payload[pos] = v[e];
    }
}

// ================= stem elementwise =================
__global__ __launch_bounds__(256) void stem_pre(const float* __restrict__ in2,
    const float* __restrict__ W1, const float* __restrict__ b1,
    unsigned short* __restrict__ H, int N)
{
    int idx = blockIdx.x * 256 + threadIdx.x;
    if (idx >= N * C) return;
    int n = idx >> 7, c = idx & 127;
    float h = fmaxf(0.f, fmaf(in2[2 * n], W1[c], fmaf(in2[2 * n + 1], W1[C + c], b1[c])));
    H[idx] = f2bf(h);
}

// ================= dense GEMM (stems + ctr2) =================
__global__ __launch_bounds__(256) void gemm_dense(const unsigned short* __restrict__ X,
    const unsigned short* __restrict__ WT, float* __restrict__ Y, int N)
{
    __shared__ unsigned short Xs[128][136];
    __shared__ unsigned short Ws[128][136];
    int tid = threadIdx.x;
    int base = blockIdx.x * 128;

    {
        int r = tid >> 1, h = (tid & 1) * 64;
        int gr = base + r; if (gr >= N) gr = N - 1;
        const uint4* src = (const uint4*)(X + (size_t)gr * C + h);
        uint4* dst = (uint4*)(&Xs[r][h]);
        #pragma unroll
        for (int it = 0; it < 8; ++it) dst[it] = src[it];
    }
    {
        int r = tid >> 1, h = (tid & 1) * 64;
        const uint4* src = (const uint4*)(WT + (size_t)r * C + h);
        uint4* dst = (uint4*)(&Ws[r][h]);
        #pragma unroll
        for (int it = 0; it < 8; ++it) dst[it] = src[it];
    }
    __syncthreads();

    int w = tid >> 6, l = tid & 63;
    int lr = l & 15, lk = (l >> 4) * 8;
    f32x4 acc[2][8];
    #pragma unroll
    for (int m = 0; m < 2; ++m)
        #pragma unroll
        for (int n = 0; n < 8; ++n) acc[m][n] = (f32x4){0.f, 0.f, 0.f, 0.f};

    #pragma unroll
    for (int kk = 0; kk < 4; ++kk) {
        bf16x8 a0 = *(const bf16x8*)&Xs[w * 32 + lr][kk * 32 + lk];
        bf16x8 a1 = *(const bf16x8*)&Xs[w * 32 + 16 + lr][kk * 32 + lk];
        #pragma unroll
        for (int n = 0; n < 8; ++n) {
            bf16x8 b = *(const bf16x8*)&Ws[n * 16 + lr][kk * 32 + lk];
            acc[0][n] = __builtin_amdgcn_mfma_f32_16x16x32_bf16(a0, b, acc[0][n], 0, 0, 0);
            acc[1][n] = __builtin_amdgcn_mfma_f32_16x16x32_bf16(a1, b, acc[1][n], 0, 0, 0);
        }
    }

    #pragma unroll
    for (int m = 0; m < 2; ++m)
        #pragma unroll
        for (int n = 0; n < 8; ++n)
            #pragma unroll
            for (int q = 0; q < 4; ++q) {
                int row = base + w * 32 + m * 16 + (l >> 4) * 4 + q;
                if (row < N) Y[(size_t)row * C + n * 16 + lr] = acc[m][n][q];
            }
}

// ================= fused edge kernel (owner-computes over 64 dsts) =================
__device__ __forceinline__ void load_b(const unsigned short* wt, bf16x8 (&bfr)[2][4], int w, int l)
{
    int lr = l & 15, lk = (l >> 4) * 8;
    #pragma unroll
    for (int nn = 0; nn < 2; ++nn)
        #pragma unroll
        for (int kk = 0; kk < 4; ++kk)
            bfr[nn][kk] = *(const bf16x8*)(wt + ((size_t)((w * 2 + nn) * 16 + lr)) * C + kk * 32 + lk);
}

__device__ __forceinline__ void mfma_accum(const unsigned short (&Xs)[64][136],
    float (&acc)[65][132], const int (&ldl)[64], const bf16x8 (&bfr)[2][4], int w, int l)
{
    int lr = l & 15, lk = (l >> 4) * 8;
    #pragma unroll
    for (int m = 0; m < 4; ++m) {
        bf16x8 a[4];
        #pragma unroll
        for (int kk = 0; kk < 4; ++kk)
            a[kk] = *(const bf16x8*)&Xs[m * 16 + lr][kk * 32 + lk];
        f32x4 acc2[2];
        acc2[0] = (f32x4){0.f, 0.f, 0.f, 0.f};
        acc2[1] = (f32x4){0.f, 0.f, 0.f, 0.f};
        #pragma unroll
        for (int nn = 0; nn < 2; ++nn)
            #pragma unroll
            for (int kk = 0; kk < 4; ++kk)
                acc2[nn] = __builtin_amdgcn_mfma_f32_16x16x32_bf16(a[kk], bfr[nn][kk], acc2[nn], 0, 0, 0);
        int dls[4];
        #pragma unroll
        for (int q = 0; q < 4; ++q) dls[q] = ldl[m * 16 + (l >> 4) * 4 + q];
        #pragma unroll
        for (int nn = 0; nn < 2; ++nn) {
            int ch = (w * 2 + nn) * 16 + lr;
            #pragma unroll
            for (int q = 0; q < 4; ++q)
                atomicAdd(&acc[dls[q]][ch], acc2[nn][q]);
        }
    }
}

__global__ __launch_bounds__(256) void fused_edge(const unsigned short* __restrict__ featB,
    const int* __restrict__ payload, const int* __restrict__ off,
    const unsigned short* __restrict__ WTb, float* __restrict__ T, int N)
{
    __shared__ float acc[65][132];          // 64 dsts + 1 trash row
    __shared__ unsigned short Xs[64][136];
    __shared__ int soff[65];
    __shared__ int ldl[64];

    int tid = threadIdx.x;
    int w = tid >> 6, l = tid & 63;
    int base = blockIdx.x * 64;             // N % 64 == 0
    int r = tid >> 2, part = tid & 3;

    // zero acc
    {
        float4* az = (float4*)&acc[0][0];
        #pragma unroll
        for (int i = 0; i < 9; ++i) {
            int idx = tid + i * 256;
            if (idx < 65 * 33) az[idx] = make_float4(0.f, 0.f, 0.f, 0.f);
        }
    }

    bf16x8 bfr[2][4];

    // ---- dense ctr init (W index 0) ----
    load_b(WTb, bfr, w, l);
    if (part == 0) ldl[r] = r;
    {
        const uint4* sp = (const uint4*)(featB + (size_t)(base + r) * C + part * 32);
        uint4* dp = (uint4*)&Xs[r][part * 32];
        #pragma unroll
        for (int j = 0; j < 4; ++j) dp[j] = sp[j];
    }
    __syncthreads();
    mfma_accum(Xs, acc, ldl, bfr, w, l);
    __syncthreads();

    // ---- 14 edge sets ----
    for (int cs = 0; cs < 14; ++cs) {
        __syncthreads();                                 // protect soff across sets
        if (tid < 65) soff[tid] = off[(size_t)cs * N + base + tid];
        load_b(WTb + (size_t)(cs + 1) * C * C, bfr, w, l);
        __syncthreads();
        int cb = soff[0], end = soff[64];
        for (int cstart = cb; cstart < end; cstart += 64) {
            int p = cstart + r;
            int src = 0, dl = 64;
            if (p < end) {
                src = payload[p];
                int lo = 0, hi = 64;                     // soff[lo] <= p < soff[hi]
                while (hi - lo > 1) { int mid = (lo + hi) >> 1; if (soff[mid] <= p) lo = mid; else hi = mid; }
                dl = lo;
            }
            if (part == 0) ldl[r] = dl;
            const uint4* sp = (const uint4*)(featB + (size_t)src * C + part * 32);
            uint4* dp = (uint4*)&Xs[r][part * 32];
            #pragma unroll
            for (int j = 0; j < 4; ++j) dp[j] = sp[j];
            __syncthreads();
            mfma_accum(Xs, acc, ldl, bfr, w, l);
            __syncthreads();
        }
    }

    __syncthreads();
    // ---- epilogue: plain store ----
    {
        int d = tid >> 2, co = (tid & 3) * 32;
        float4* tr = (float4*)(T + (size_t)(base + d) * C + co);
        #pragma unroll
        for (int j = 0; j < 8; ++j) tr[j] = *(const float4*)&acc[d][co + j * 4];
    }
}

// ================= GroupNorm kernels (2 rows / 256-thread block) =================
__device__ __forceinline__ float grp_sum(float v, int tid, float* red) {
    for (int off = 32; off; off >>= 1) v += __shfl_down(v, off, 64);
    __syncthreads();
    if ((tid & 63) == 0) red[tid >> 6] = v;
    __syncthreads();
    int grp = tid >> 7;
    return red[grp * 2] + red[grp * 2 + 1];
}

__global__ __launch_bounds__(256) void stem_gnA(const float* __restrict__ Y,
    const float* __restrict__ g, const float* __restrict__ b, float* __restrict__ A)
{
    __shared__ float red[4];
    int tid = threadIdx.x;
    int n = blockIdx.x * 2 + (tid >> 7), c = tid & 127;
    size_t idx = (size_t)n * C + c;
    float y = Y[idx];
    float m = grp_sum(y, tid, red) * (1.f / C);
    float d = y - m;
    float var = grp_sum(d * d, tid, red) * (1.f / C);
    A[idx] = d * rsqrtf(var + EPS) * g[c] + b[c];
}

__global__ __launch_bounds__(256) void stem_gnB(const float* __restrict__ Y,
    const float* __restrict__ g, const float* __restrict__ b,
    float* __restrict__ A, unsigned short* __restrict__ featB)
{
    __shared__ float red[4];
    int tid = threadIdx.x;
    int n = blockIdx.x * 2 + (tid >> 7), c = tid & 127;
    size_t idx = (size_t)n * C + c;
    float y = Y[idx];
    float m = grp_sum(y, tid, red) * (1.f / C);
    float d = y - m;
    float var = grp_sum(d * d, tid, red) * (1.f / C);
    float o = d * rsqrtf(var + EPS) * g[c] + b[c];
    float r = fmaxf(0.f, A[idx] + o);
    A[idx] = r;
    featB[idx] = f2bf(r);
}

__global__ __launch_bounds__(256) void tail_gn1(const float* __restrict__ T,
    const float* __restrict__ g, const float* __restrict__ b, unsigned short* __restrict__ Xb)
{
    __shared__ float red[4];
    int tid = threadIdx.x;
    int n = blockIdx.x * 2 + (tid >> 7), c = tid & 127;
    size_t idx = (size_t)n * C + c;
    float y = T[idx];
    float m = grp_sum(y, tid, red) * (1.f / C);
    float d = y - m;
    float var = grp_sum(d * d, tid, red) * (1.f / C);
    Xb[idx] = f2bf(fmaxf(0.f, d * rsqrtf(var + EPS) * g[c] + b[c]));
}

__global__ __launch_bounds__(256) void tail_gn2(float* __restrict__ Y,
    const float* __restrict__ g, const float* __restrict__ b,
    float* __restrict__ A, unsigned short* __restrict__ featB)
{
    __shared__ float red[4];
    int tid = threadIdx.x;
    int n = blockIdx.x * 2 + (tid >> 7), c = tid & 127;
    size_t idx = (size_t)n * C + c;
    float y = Y[idx];
    float m = grp_sum(y, tid, red) * (1.f / C);
    float d = y - m;
    float var = grp_sum(d * d, tid, red) * (1.f / C);
    float o = d * rsqrtf(var + EPS) * g[c] + b[c];
    float r = fmaxf(0.f, A[idx] + o);
    A[idx] = r;
    featB[idx] = f2bf(r);
    Y[idx] = r;
}

// ================= launch =================
extern "C" void kernel_launch(void* const* d_in, const int* in_sizes, int n_in,
                              void* d_out, int out_size, void* d_ws, size_t ws_size,
                              hipStream_t stream)
{
    const float* ctrs   = (const float*)d_in[0];
    const float* feats  = (const float*)d_in[1];
    const int*   pre_u  = (const int*)d_in[2];
    const int*   pre_v  = (const int*)d_in[3];
    const int*   suc_u  = (const int*)d_in[4];
    const int*   suc_v  = (const int*)d_in[5];
    const int*   left_u = (const int*)d_in[6];
    const int*   left_v = (const int*)d_in[7];
    const int*   right_u= (const int*)d_in[8];
    const int*   right_v= (const int*)d_in[9];
    const float* W_in1  = (const float*)d_in[10];
    const float* b_in1  = (const float*)d_in[11];
    const float* W_in2  = (const float*)d_in[12];
    const float* g_in   = (const float*)d_in[13];
    const float* bb_in  = (const float*)d_in[14];
    const float* W_seg1 = (const float*)d_in[15];
    const float* b_seg1 = (const float*)d_in[16];
    const float* W_seg2 = (const float*)d_in[17];
    const float* g_seg  = (const float*)d_in[18];
    const float* bb_seg = (const float*)d_in[19];
    const float* W_ctr  = (const float*)d_in[20];
    const float* W_pre  = (const float*)d_in[21];
    const float* W_suc  = (const float*)d_in[22];
    const float* W_left = (const float*)d_in[23];
    const float* W_right= (const float*)d_in[24];
    const float* g_norm = (const float*)d_in[25];
    const float* b_norm = (const float*)d_in[26];
    const float* W_ctr2 = (const float*)d_in[27];
    const float* g_ctr2 = (const float*)d_in[28];
    const float* b_ctr2 = (const float*)d_in[29];

    const int N  = in_sizes[0] / 2;          // 200000
    const int S  = 6;
    const int E  = in_sizes[2] / S;          // 200000
    const int E2 = in_sizes[6];              // 100000
    const int B  = in_sizes[20] / (C * C);   // 2
    const int CC = C * C;
    const int M  = 14 * N;                   // CSR bins
    const int ET = 12 * E + 2 * E2;          // total edges

    // ---- workspace layout ----
    float* A = (float*)d_ws;                                   // N*C f32
    unsigned short* featB = (unsigned short*)(A + (size_t)N * C);   // N*C bf16
    unsigned short* WT = featB + (size_t)N * C;                // 34*CC bf16
    int* off     = (int*)(WT + (size_t)34 * CC);               // M+1 (+pad to 4)
    int* cursor  = off + (M + 4);                              // M  (deg then cursor)
    int* payload = cursor + M;                                 // ET
    int* bsum    = payload + ET;                               // ~700
    float* T = (float*)d_out;

    WPtrs wp;
    wp.p[0] = W_in2; wp.p[1] = W_seg2;
    for (int i = 0; i < B; ++i) {
        int wbase = 2 + i * 16;
        wp.p[wbase + 0] = W_ctr + (size_t)i * CC;
        for (int s = 0; s < S; ++s) {
            wp.p[wbase + 1 + s] = W_pre + ((size_t)i * S + s) * CC;
            wp.p[wbase + 7 + s] = W_suc + ((size_t)i * S + s) * CC;
        }
        wp.p[wbase + 13] = W_left  + (size_t)i * CC;
        wp.p[wbase + 14] = W_right + (size_t)i * CC;
        wp.p[wbase + 15] = W_ctr2  + (size_t)i * CC;
    }

    const int GT = (N + 127) / 128;
    const int GEx = (E + 255) / 256;         // covers E2 too
    const int NB_SCAN = (M + 4095) / 4096;
    dim3 b256(256), b128(128);

    convert_weights<<<dim3(128, 34), b128, 0, stream>>>(wp, WT);

    // ---- CSR build ----
    hipMemsetAsync(cursor, 0, (size_t)M * 4, stream);
    hist_k<<<dim3(GEx, 14), b256, 0, stream>>>(pre_u, suc_u, left_u, right_u, cursor, E, E2, N);
    scan1<<<NB_SCAN, b256, 0, stream>>>(cursor, off, bsum, M);
    scan2<<<1, b256, 0, stream>>>(bsum, NB_SCAN);
    scan3<<<(M + 255) / 256, b256, 0, stream>>>(off, cursor, bsum, M);
    scatter_k<<<dim3(GEx, 14), b256, 0, stream>>>(pre_u, pre_v, suc_u, suc_v,
        left_u, left_v, right_u, right_v, cursor, payload, E, E2, N);

    // ---- stem ----
    stem_pre<<<(N * C + 255) / 256, b256, 0, stream>>>(ctrs, W_in1, b_in1, featB, N);
    gemm_dense<<<GT, b256, 0, stream>>>(featB, WT + 0 * (size_t)CC, T, N);
    stem_gnA<<<N / 2, b256, 0, stream>>>(T, g_in, bb_in, A);
    stem_pre<<<(N * C + 255) / 256, b256, 0, stream>>>(feats, W_seg1, b_seg1, featB, N);
    gemm_dense<<<GT, b256, 0, stream>>>(featB, WT + 1 * (size_t)CC, T, N);
    stem_gnB<<<N / 2, b256, 0, stream>>>(T, g_seg, bb_seg, A, featB);

    // ---- fusion blocks ----
    for (int i = 0; i < B; ++i) {
        const unsigned short* WTb = WT + (size_t)(2 + i * 16) * CC;
        fused_edge<<<N / 64, b256, 0, stream>>>(featB, payload, off, WTb, T, N);
        tail_gn1<<<N / 2, b256, 0, stream>>>(T, g_norm + (size_t)i * C, b_norm + (size_t)i * C, featB);
        gemm_dense<<<GT, b256, 0, stream>>>(featB, WTb + 15 * (size_t)CC, T, N);
        tail_gn2<<<N / 2, b256, 0, stream>>>(T, g_ctr2 + (size_t)i * C, b_ctr2 + (size_t)i * C, A, featB);
    }
}

// Round 12
// 6849.511 us; speedup vs baseline: 1.0337x; 1.0337x over previous
//
#include <hip/hip_runtime.h>

#define C 128
#define EPS 1e-5f

typedef __bf16 bf16x8 __attribute__((ext_vector_type(8)));
typedef float f32x4 __attribute__((ext_vector_type(4)));

__device__ __forceinline__ unsigned short f2bf(float f) {
    unsigned int u = __float_as_uint(f);
    unsigned int r = (u + 0x7FFFu + ((u >> 16) & 1u)) >> 16;   // RNE
    return (unsigned short)r;
}

// ---------------- weight convert: WT[m][col][k] = bf16(W_m[k][col]) ----------------
struct WPtrs { const float* p[34]; };

__global__ __launch_bounds__(128) void convert_weights(WPtrs wp, unsigned short* __restrict__ WT)
{
    int m = blockIdx.y, k = blockIdx.x, c = threadIdx.x;      // grid (128, 34)
    float val = wp.p[m][k * C + c];
    WT[((size_t)m * C + c) * C + k] = f2bf(val);
}

// ================= CSR preprocessing =================
__global__ __launch_bounds__(256) void hist_k(const int* __restrict__ pre_u,
    const int* __restrict__ suc_u, const int* __restrict__ left_u, const int* __restrict__ right_u,
    int* __restrict__ deg, int E, int E2, int N)
{
    int cs = blockIdx.y;
    const int* u; int len;
    if (cs < 6)       { u = pre_u + (size_t)cs * E;       len = E; }
    else if (cs < 12) { u = suc_u + (size_t)(cs - 6) * E; len = E; }
    else if (cs == 12){ u = left_u;  len = E2; }
    else              { u = right_u; len = E2; }
    int e = blockIdx.x * 256 + threadIdx.x;
    if (e < len) atomicAdd(&deg[(size_t)cs * N + u[e]], 1);
}

__global__ __launch_bounds__(256) void scan1(const int* __restrict__ deg, int* __restrict__ off,
                                             int* __restrict__ bsum, int M)
{
    __shared__ int ts[256];
    int b = blockIdx.x, t = threadIdx.x;
    int base = b * 4096 + t * 16;
    int v[16]; int s = 0;
    #pragma unroll
    for (int j = 0; j < 16; ++j) { int idx = base + j; int x = (idx < M) ? deg[idx] : 0; v[j] = s; s += x; }
    ts[t] = s; __syncthreads();
    for (int o = 1; o < 256; o <<= 1) {
        int x = (t >= o) ? ts[t - o] : 0;
        __syncthreads(); ts[t] += x; __syncthreads();
    }
    int texcl = (t == 0) ? 0 : ts[t - 1];
    if (t == 255) bsum[b] = ts[255];
    #pragma unroll
    for (int j = 0; j < 16; ++j) { int idx = base + j; if (idx < M) off[idx] = texcl + v[j]; }
}

__global__ void scan2(int* __restrict__ bsum, int nb)
{
    __shared__ int s[1024];
    int t = threadIdx.x;
    for (int i = t; i < 1024; i += 256) s[i] = (i < nb) ? bsum[i] : 0;
    __syncthreads();
    if (t == 0) { int run = 0; for (int i = 0; i < nb; ++i) { int x = s[i]; s[i] = run; run += x; } }
    __syncthreads();
    for (int i = t; i < nb; i += 256) bsum[i] = s[i];
}

__global__ __launch_bounds__(256) void scan3(int* __restrict__ off, int* __restrict__ cursor,
                                             const int* __restrict__ bsum, int M)
{
    int i = blockIdx.x * 256 + threadIdx.x;
    if (i >= M) return;
    int val = off[i] + bsum[i >> 12];
    int dg = cursor[i];
    off[i] = val; cursor[i] = val;
    if (i == M - 1) off[M] = val + dg;
}

// payload packs (dl<<18)|v  where dl = u&63 (tile-local dst), v < 2^18
__global__ __launch_bounds__(256) void scatter_k(const int* __restrict__ pre_u, const int* __restrict__ pre_v,
    const int* __restrict__ suc_u, const int* __restrict__ suc_v,
    const int* __restrict__ left_u, const int* __restrict__ left_v,
    const int* __restrict__ right_u, const int* __restrict__ right_v,
    int* __restrict__ cursor, unsigned int* __restrict__ payload, int E, int E2, int N)
{
    int cs = blockIdx.y;
    const int *u, *v; int len;
    if (cs < 6)       { u = pre_u + (size_t)cs * E;       v = pre_v + (size_t)cs * E;       len = E; }
    else if (cs < 12) { u = suc_u + (size_t)(cs - 6) * E; v = suc_v + (size_t)(cs - 6) * E; len = E; }
    else if (cs == 12){ u = left_u;  v = left_v;  len = E2; }
    else              { u = right_u; v = right_v; len = E2; }
    int e = blockIdx.x * 256 + threadIdx.x;
    if (e < len) {
        int uu = u[e];
        int pos = atomicAdd(&cursor[(size_t)cs * N + uu], 1);
        payload[pos] = (unsigned int)v[e] | ((unsigned int)(uu & 63) << 18);
    }
}

// ================= stem elementwise =================
__global__ __launch_bounds__(256) void stem_pre(const float* __restrict__ in2,
    const float* __restrict__ W1, const float* __restrict__ b1,
    unsigned short* __restrict__ H, int N)
{
    int idx = blockIdx.x * 256 + threadIdx.x;
    if (idx >= N * C) return;
    int n = idx >> 7, c = idx & 127;
    float h = fmaxf(0.f, fmaf(in2[2 * n], W1[c], fmaf(in2[2 * n + 1], W1[C + c], b1[c])));
    H[idx] = f2bf(h);
}

// ================= dense GEMM (stems + ctr2) =================
__global__ __launch_bounds__(256) void gemm_dense(const unsigned short* __restrict__ X,
    const unsigned short* __restrict__ WT, float* __restrict__ Y, int N)
{
    __shared__ unsigned short Xs[128][136];
    __shared__ unsigned short Ws[128][136];
    int tid = threadIdx.x;
    int base = blockIdx.x * 128;

    {
        int r = tid >> 1, h = (tid & 1) * 64;
        int gr = base + r; if (gr >= N) gr = N - 1;
        const uint4* src = (const uint4*)(X + (size_t)gr * C + h);
        uint4* dst = (uint4*)(&Xs[r][h]);
        #pragma unroll
        for (int it = 0; it < 8; ++it) dst[it] = src[it];
    }
    {
        int r = tid >> 1, h = (tid & 1) * 64;
        const uint4* src = (const uint4*)(WT + (size_t)r * C + h);
        uint4* dst = (uint4*)(&Ws[r][h]);
        #pragma unroll
        for (int it = 0; it < 8; ++it) dst[it] = src[it];
    }
    __syncthreads();

    int w = tid >> 6, l = tid & 63;
    int lr = l & 15, lk = (l >> 4) * 8;
    f32x4 acc[2][8];
    #pragma unroll
    for (int m = 0; m < 2; ++m)
        #pragma unroll
        for (int n = 0; n < 8; ++n) acc[m][n] = (f32x4){0.f, 0.f, 0.f, 0.f};

    #pragma unroll
    for (int kk = 0; kk < 4; ++kk) {
        bf16x8 a0 = *(const bf16x8*)&Xs[w * 32 + lr][kk * 32 + lk];
        bf16x8 a1 = *(const bf16x8*)&Xs[w * 32 + 16 + lr][kk * 32 + lk];
        #pragma unroll
        for (int n = 0; n < 8; ++n) {
            bf16x8 b = *(const bf16x8*)&Ws[n * 16 + lr][kk * 32 + lk];
            acc[0][n] = __builtin_amdgcn_mfma_f32_16x16x32_bf16(a0, b, acc[0][n], 0, 0, 0);
            acc[1][n] = __builtin_amdgcn_mfma_f32_16x16x32_bf16(a1, b, acc[1][n], 0, 0, 0);
        }
    }

    #pragma unroll
    for (int m = 0; m < 2; ++m)
        #pragma unroll
        for (int n = 0; n < 8; ++n)
            #pragma unroll
            for (int q = 0; q < 4; ++q) {
                int row = base + w * 32 + m * 16 + (l >> 4) * 4 + q;
                if (row < N) Y[(size_t)row * C + n * 16 + lr] = acc[m][n][q];
            }
}

// ================= fused edge kernel v2: per-wave set streaming, no barriers =================
// Each wave owns sets {4w..4w+3}; set 14 = dense ctr rows. A gathered global->reg,
// B streamed from L2-resident WT, C scattered via LDS ds_add into shared acc.
__global__ __launch_bounds__(256) void fused_edge(const unsigned short* __restrict__ featB,
    const unsigned int* __restrict__ payload, const int* __restrict__ off,
    const unsigned short* __restrict__ WTb, float* __restrict__ T, int N)
{
    __shared__ float acc[65][132];          // 64 dsts + 1 trash row
    int tid = threadIdx.x;
    int w = tid >> 6, l = tid & 63;
    int base = blockIdx.x * 64;             // N % 64 == 0
    int lr16 = l & 15, lq = l >> 4;         // lq in 0..3
    int lk = lq * 8;                        // bf16-element k offset within a 32-k block

    // zero acc: 65*132 floats = 65*33 float4
    {
        float4* az = (float4*)&acc[0][0];
        for (int i = tid; i < 65 * 33; i += 256) az[i] = make_float4(0.f, 0.f, 0.f, 0.f);
    }
    __syncthreads();

    #pragma unroll 1
    for (int sci = 0; sci < 4; ++sci) {
        int cs = w * 4 + sci;
        if (cs > 14) break;
        int cb, ce;
        const unsigned short* Wt;
        if (cs == 14) { cb = 0; ce = 64; Wt = WTb; }                 // dense ctr (W idx 0)
        else {
            cb = off[(size_t)cs * N + base];
            ce = off[(size_t)cs * N + base + 64];
            Wt = WTb + (size_t)(cs + 1) * C * C;
        }
        #pragma unroll 1
        for (int c0 = cb; c0 < ce; c0 += 64) {
            // ---- payload + direct A gather (64 rows, 16 per m-block) ----
            bf16x8 a[4][4];
            int dlm[4];
            #pragma unroll
            for (int m = 0; m < 4; ++m) {
                unsigned int p;
                if (cs == 14) {
                    p = (unsigned int)(base + m * 16 + lr16) | ((unsigned int)(m * 16 + lr16) << 18);
                } else {
                    int row = c0 + m * 16 + lr16;
                    p = (row < ce) ? payload[row] : (64u << 18);
                }
                int v  = (int)(p & 0x3FFFFu);
                dlm[m] = (int)(p >> 18);
                const unsigned short* src = featB + (size_t)v * C;
                #pragma unroll
                for (int kk = 0; kk < 4; ++kk)
                    a[m][kk] = *(const bf16x8*)(src + kk * 32 + lk);
            }
            // C-row dls: row rr = lq*4+q of m-block is held by lane rr
            int dsc[4][4];
            #pragma unroll
            for (int m = 0; m < 4; ++m)
                #pragma unroll
                for (int q = 0; q < 4; ++q)
                    dsc[m][q] = __shfl(dlm[m], lq * 4 + q, 64);

            // ---- stream B (2 col-blocks at a time), MFMA, LDS scatter ----
            #pragma unroll 1
            for (int np = 0; np < 4; ++np) {
                bf16x8 bfr[2][4];
                #pragma unroll
                for (int nn = 0; nn < 2; ++nn)
                    #pragma unroll
                    for (int kk = 0; kk < 4; ++kk)
                        bfr[nn][kk] = *(const bf16x8*)(Wt + (size_t)((np * 2 + nn) * 16 + lr16) * C + kk * 32 + lk);
                int ch0 = (np * 2) * 16 + lr16, ch1 = (np * 2 + 1) * 16 + lr16;
                #pragma unroll
                for (int m = 0; m < 4; ++m) {
                    f32x4 c0v = (f32x4){0.f, 0.f, 0.f, 0.f};
                    f32x4 c1v = (f32x4){0.f, 0.f, 0.f, 0.f};
                    #pragma unroll
                    for (int kk = 0; kk < 4; ++kk) {
                        c0v = __builtin_amdgcn_mfma_f32_16x16x32_bf16(a[m][kk], bfr[0][kk], c0v, 0, 0, 0);
                        c1v = __builtin_amdgcn_mfma_f32_16x16x32_bf16(a[m][kk], bfr[1][kk], c1v, 0, 0, 0);
                    }
                    #pragma unroll
                    for (int q = 0; q < 4; ++q) {
                        atomicAdd(&acc[dsc[m][q]][ch0], c0v[q]);
                        atomicAdd(&acc[dsc[m][q]][ch1], c1v[q]);
                    }
                }
            }
        }
    }

    __syncthreads();
    // ---- epilogue: plain store of 64 rows ----
    {
        int d = tid >> 2, co = (tid & 3) * 32;
        float4* tr = (float4*)(T + (size_t)(base + d) * C + co);
        #pragma unroll
        for (int j = 0; j < 8; ++j) tr[j] = *(const float4*)&acc[d][co + j * 4];
    }
}

// ================= GroupNorm kernels (2 rows / 256-thread block) =================
__device__ __forceinline__ float grp_sum(float v, int tid, float* red) {
    for (int off = 32; off; off >>= 1) v += __shfl_down(v, off, 64);
    __syncthreads();
    if ((tid & 63) == 0) red[tid >> 6] = v;
    __syncthreads();
    int grp = tid >> 7;
    return red[grp * 2] + red[grp * 2 + 1];
}

__global__ __launch_bounds__(256) void stem_gnA(const float* __restrict__ Y,
    const float* __restrict__ g, const float* __restrict__ b, float* __restrict__ A)
{
    __shared__ float red[4];
    int tid = threadIdx.x;
    int n = blockIdx.x * 2 + (tid >> 7), c = tid & 127;
    size_t idx = (size_t)n * C + c;
    float y = Y[idx];
    float m = grp_sum(y, tid, red) * (1.f / C);
    float d = y - m;
    float var = grp_sum(d * d, tid, red) * (1.f / C);
    A[idx] = d * rsqrtf(var + EPS) * g[c] + b[c];
}

__global__ __launch_bounds__(256) void stem_gnB(const float* __restrict__ Y,
    const float* __restrict__ g, const float* __restrict__ b,
    float* __restrict__ A, unsigned short* __restrict__ featB)
{
    __shared__ float red[4];
    int tid = threadIdx.x;
    int n = blockIdx.x * 2 + (tid >> 7), c = tid & 127;
    size_t idx = (size_t)n * C + c;
    float y = Y[idx];
    float m = grp_sum(y, tid, red) * (1.f / C);
    float d = y - m;
    float var = grp_sum(d * d, tid, red) * (1.f / C);
    float o = d * rsqrtf(var + EPS) * g[c] + b[c];
    float r = fmaxf(0.f, A[idx] + o);
    A[idx] = r;
    featB[idx] = f2bf(r);
}

__global__ __launch_bounds__(256) void tail_gn1(const float* __restrict__ T,
    const float* __restrict__ g, const float* __restrict__ b, unsigned short* __restrict__ Xb)
{
    __shared__ float red[4];
    int tid = threadIdx.x;
    int n = blockIdx.x * 2 + (tid >> 7), c = tid & 127;
    size_t idx = (size_t)n * C + c;
    float y = T[idx];
    float m = grp_sum(y, tid, red) * (1.f / C);
    float d = y - m;
    float var = grp_sum(d * d, tid, red) * (1.f / C);
    Xb[idx] = f2bf(fmaxf(0.f, d * rsqrtf(var + EPS) * g[c] + b[c]));
}

__global__ __launch_bounds__(256) void tail_gn2(float* __restrict__ Y,
    const float* __restrict__ g, const float* __restrict__ b,
    float* __restrict__ A, unsigned short* __restrict__ featB)
{
    __shared__ float red[4];
    int tid = threadIdx.x;
    int n = blockIdx.x * 2 + (tid >> 7), c = tid & 127;
    size_t idx = (size_t)n * C + c;
    float y = Y[idx];
    float m = grp_sum(y, tid, red) * (1.f / C);
    float d = y - m;
    float var = grp_sum(d * d, tid, red) * (1.f / C);
    float o = d * rsqrtf(var + EPS) * g[c] + b[c];
    float r = fmaxf(0.f, A[idx] + o);
    A[idx] = r;
    featB[idx] = f2bf(r);
    Y[idx] = r;
}

// ================= launch =================
extern "C" void kernel_launch(void* const* d_in, const int* in_sizes, int n_in,
                              void* d_out, int out_size, void* d_ws, size_t ws_size,
                              hipStream_t stream)
{
    const float* ctrs   = (const float*)d_in[0];
    const float* feats  = (const float*)d_in[1];
    const int*   pre_u  = (const int*)d_in[2];
    const int*   pre_v  = (const int*)d_in[3];
    const int*   suc_u  = (const int*)d_in[4];
    const int*   suc_v  = (const int*)d_in[5];
    const int*   left_u = (const int*)d_in[6];
    const int*   left_v = (const int*)d_in[7];
    const int*   right_u= (const int*)d_in[8];
    const int*   right_v= (const int*)d_in[9];
    const float* W_in1  = (const float*)d_in[10];
    const float* b_in1  = (const float*)d_in[11];
    const float* W_in2  = (const float*)d_in[12];
    const float* g_in   = (const float*)d_in[13];
    const float* bb_in  = (const float*)d_in[14];
    const float* W_seg1 = (const float*)d_in[15];
    const float* b_seg1 = (const float*)d_in[16];
    const float* W_seg2 = (const float*)d_in[17];
    const float* g_seg  = (const float*)d_in[18];
    const float* bb_seg = (const float*)d_in[19];
    const float* W_ctr  = (const float*)d_in[20];
    const float* W_pre  = (const float*)d_in[21];
    const float* W_suc  = (const float*)d_in[22];
    const float* W_left = (const float*)d_in[23];
    const float* W_right= (const float*)d_in[24];
    const float* g_norm = (const float*)d_in[25];
    const float* b_norm = (const float*)d_in[26];
    const float* W_ctr2 = (const float*)d_in[27];
    const float* g_ctr2 = (const float*)d_in[28];
    const float* b_ctr2 = (const float*)d_in[29];

    const int N  = in_sizes[0] / 2;          // 200000
    const int S  = 6;
    const int E  = in_sizes[2] / S;          // 200000
    const int E2 = in_sizes[6];              // 100000
    const int B  = in_sizes[20] / (C * C);   // 2
    const int CC = C * C;
    const int M  = 14 * N;                   // CSR bins
    const int ET = 12 * E + 2 * E2;          // total edges

    // ---- workspace layout ----
    float* A = (float*)d_ws;                                        // N*C f32
    unsigned short* featB = (unsigned short*)(A + (size_t)N * C);   // N*C bf16
    unsigned short* WT = featB + (size_t)N * C;                     // 34*CC bf16
    int* off     = (int*)(WT + (size_t)34 * CC);                    // M+1 (+pad)
    int* cursor  = off + (M + 4);                                   // M (deg then cursor)
    unsigned int* payload = (unsigned int*)(cursor + M);            // ET
    int* bsum    = (int*)(payload + ET);                            // ~700
    float* T = (float*)d_out;

    WPtrs wp;
    wp.p[0] = W_in2; wp.p[1] = W_seg2;
    for (int i = 0; i < B; ++i) {
        int wbase = 2 + i * 16;
        wp.p[wbase + 0] = W_ctr + (size_t)i * CC;
        for (int s = 0; s < S; ++s) {
            wp.p[wbase + 1 + s] = W_pre + ((size_t)i * S + s) * CC;
            wp.p[wbase + 7 + s] = W_suc + ((size_t)i * S + s) * CC;
        }
        wp.p[wbase + 13] = W_left  + (size_t)i * CC;
        wp.p[wbase + 14] = W_right + (size_t)i * CC;
        wp.p[wbase + 15] = W_ctr2  + (size_t)i * CC;
    }

    const int GT = (N + 127) / 128;
    const int GEx = (E + 255) / 256;
    const int NB_SCAN = (M + 4095) / 4096;
    dim3 b256(256), b128(128);

    convert_weights<<<dim3(128, 34), b128, 0, stream>>>(wp, WT);

    // ---- CSR build ----
    hipMemsetAsync(cursor, 0, (size_t)M * 4, stream);
    hist_k<<<dim3(GEx, 14), b256, 0, stream>>>(pre_u, suc_u, left_u, right_u, cursor, E, E2, N);
    scan1<<<NB_SCAN, b256, 0, stream>>>(cursor, off, bsum, M);
    scan2<<<1, b256, 0, stream>>>(bsum, NB_SCAN);
    scan3<<<(M + 255) / 256, b256, 0, stream>>>(off, cursor, bsum, M);
    scatter_k<<<dim3(GEx, 14), b256, 0, stream>>>(pre_u, pre_v, suc_u, suc_v,
        left_u, left_v, right_u, right_v, cursor, payload, E, E2, N);

    // ---- stem ----
    stem_pre<<<(N * C + 255) / 256, b256, 0, stream>>>(ctrs, W_in1, b_in1, featB, N);
    gemm_dense<<<GT, b256, 0, stream>>>(featB, WT + 0 * (size_t)CC, T, N);
    stem_gnA<<<N / 2, b256, 0, stream>>>(T, g_in, bb_in, A);
    stem_pre<<<(N * C + 255) / 256, b256, 0, stream>>>(feats, W_seg1, b_seg1, featB, N);
    gemm_dense<<<GT, b256, 0, stream>>>(featB, WT + 1 * (size_t)CC, T, N);
    stem_gnB<<<N / 2, b256, 0, stream>>>(T, g_seg, bb_seg, A, featB);

    // ---- fusion blocks ----
    for (int i = 0; i < B; ++i) {
        const unsigned short* WTb = WT + (size_t)(2 + i * 16) * CC;
        fused_edge<<<N / 64, b256, 0, stream>>>(featB, payload, off, WTb, T, N);
        tail_gn1<<<N / 2, b256, 0, stream>>>(T, g_norm + (size_t)i * C, b_norm + (size_t)i * C, featB);
        gemm_dense<<<GT, b256, 0, stream>>>(featB, WTb + 15 * (size_t)CC, T, N);
        tail_gn2<<<N / 2, b256, 0, stream>>>(T, g_ctr2 + (size_t)i * C, b_ctr2 + (size_t)i * C, A, featB);
    }
}